// Round 2
// baseline (327.322 us; speedup 1.0000x reference)
//
#include <hip/hip_runtime.h>
#include <math.h>

#define BB 16
#define NN 4096
#define DD 64
#define OO 12
#define SS 32
#define MM 12
#define AA 32

typedef float v4f __attribute__((ext_vector_type(4)));

__device__ __forceinline__ void nt_store4(float* p, float x, float y, float z, float w) {
    v4f v = {x, y, z, w};
    __builtin_nontemporal_store(v, reinterpret_cast<v4f*>(p));
}

// out layout: H_time [B,O,N,D] | attn [B,O,N,M] | gate [B,O,M]
__global__ __launch_bounds__(256, 4) void stta_kernel(
    const float* __restrict__ H, const float* __restrict__ ts_out,
    const float* __restrict__ step_emb, const float* __restrict__ key_emb,
    const float* __restrict__ val_emb, const float* __restrict__ Wk,
    const float* __restrict__ Wg, const float* __restrict__ bgp,
    const float* __restrict__ Wq, const float* __restrict__ bq,
    float* __restrict__ out)
{
    const int b = blockIdx.y;
    const int n0 = blockIdx.x * 64;
    const int tid = threadIdx.x;

    __shared__ __align__(16) float s_wq[32 * 64];       // Wq[a][d], d<64
    __shared__ __align__(16) float s_ke[MM * AA];       // key_emb[m][a]
    __shared__ __align__(16) float s_ve[MM * DD];       // val_emb[m][d]
    __shared__ __align__(16) float s_wk0[32];
    __shared__ __align__(16) float s_wk1[32];
    __shared__ __align__(16) float s_tokS[OO * MM];
    __shared__ __align__(16) float s_tokC[OO * MM];
    __shared__ __align__(16) float s_gate[OO * MM];
    __shared__ __align__(16) float s_qs[OO * AA];       // qs[o][a]
    __shared__ __align__(16) float s_c2[OO * MM];       // scale * (qs[o] . key[o,m])

    float* outH    = out;
    float* outAttn = out + (size_t)BB * OO * NN * DD;
    float* outGate = outAttn + (size_t)BB * OO * NN * MM;

    const float scale = 0.17677669529663687f; // 1/sqrt(32)

    // ---- staging (vectorized float4 copies) ----
    {
        // s_wq[a][d] = Wq[a*96 + d], d<64 : 512 float4
        float4* dst = reinterpret_cast<float4*>(s_wq);
        for (int i = tid; i < 512; i += 256) {
            int a = i >> 4, dq = i & 15;
            dst[i] = reinterpret_cast<const float4*>(Wq + a * 96)[dq];
        }
    }
    {
        float4* dst = reinterpret_cast<float4*>(s_ke);
        const float4* src = reinterpret_cast<const float4*>(key_emb);
        for (int i = tid; i < (MM * AA) / 4; i += 256) dst[i] = src[i];
    }
    {
        float4* dst = reinterpret_cast<float4*>(s_ve);
        const float4* src = reinterpret_cast<const float4*>(val_emb);
        for (int i = tid; i < (MM * DD) / 4; i += 256) dst[i] = src[i];
    }
    if (tid < 32) { s_wk0[tid] = Wk[tid * 2]; s_wk1[tid] = Wk[tid * 2 + 1]; }

    const float wg0 = Wg[0], wg1 = Wg[1], bg0 = bgp[0];
    for (int i = tid; i < OO * MM; i += 256) {
        int o = i / MM, m = i - o * MM;
        float phase = ts_out[(b * OO + o) * 2 + (m < 8 ? 0 : 1)];
        float k = (m < 8) ? (float)(m + 1) : (float)(m - 7);
        float ang = 6.283185307179586f * phase * k;
        float sv = sinf(ang), cv = cosf(ang);
        s_tokS[i] = sv; s_tokC[i] = cv;
        float gv = tanhf(sv * wg0 + cv * wg1 + bg0);
        s_gate[i] = gv;
        if (blockIdx.x == 0) outGate[(b * OO + o) * MM + m] = gv;
    }
    for (int e = tid; e < OO * AA; e += 256) {
        int o = e >> 5, a = e & 31;
        float acc = bq[a];
        const float* se = step_emb + (b * OO + o) * SS;
        const float* wq = Wq + a * 96 + 64;
        #pragma unroll
        for (int s = 0; s < SS; s++) acc += se[s] * wq[s];
        s_qs[e] = acc;
    }
    __syncthreads();

    // ---- c2[o][m] = scale * (qs[o] . key[o,m]) ----
    for (int i = tid; i < OO * MM; i += 256) {
        int o = i / MM, m = i - o * MM;
        float S = s_tokS[i], C = s_tokC[i];
        float acc = 0.f;
        const float* qs = s_qs + o * 32;
        const float* ke = s_ke + m * 32;
        #pragma unroll
        for (int a = 0; a < 32; a++)
            acc += qs[a] * (S * s_wk0[a] + C * s_wk1[a] + ke[a]);
        s_c2[i] = acc * scale;
    }
    __syncthreads();

    const int nl = tid >> 2, g = tid & 3;
    const int n = n0 + nl;

    // ---- load my 16 H values, chunk-interleaved: thread owns d-chunks
    //      {g, g+4, g+8, g+12} (each chunk = 4 floats). For a fixed jj the
    //      wave's 64 lanes then cover full 64B segments (4 lanes x 16B). ----
    const float4* hrow = reinterpret_cast<const float4*>(H + ((size_t)b * NN + n) * DD);
    float h[16];
    #pragma unroll
    for (int jj = 0; jj < 4; jj++) {
        float4 v = hrow[g + 4 * jj];
        h[jj*4+0] = v.x; h[jj*4+1] = v.y; h[jj*4+2] = v.z; h[jj*4+3] = v.w;
    }

    // ---- qh partials over my 16 d's, butterfly over the 4-lane group,
    //      then project to (uh, vh, wh[12]) — logits are linear in qh ----
    float uh = 0.f, vh = 0.f;
    float wh[12] = {0,0,0,0,0,0,0,0,0,0,0,0};
    {
        float qh[32];
        #pragma unroll
        for (int a = 0; a < 32; a++) {
            const float4* wq4 = reinterpret_cast<const float4*>(s_wq + a * 64);
            float acc = 0.f;
            #pragma unroll
            for (int jj = 0; jj < 4; jj++) {
                float4 w = wq4[g + 4 * jj];
                acc += h[jj*4+0]*w.x + h[jj*4+1]*w.y + h[jj*4+2]*w.z + h[jj*4+3]*w.w;
            }
            qh[a] = acc;
        }
        #pragma unroll
        for (int a = 0; a < 32; a++) qh[a] += __shfl_xor(qh[a], 1);
        #pragma unroll
        for (int a = 0; a < 32; a++) qh[a] += __shfl_xor(qh[a], 2);

        const float4* k0 = reinterpret_cast<const float4*>(s_wk0);
        const float4* k1 = reinterpret_cast<const float4*>(s_wk1);
        #pragma unroll
        for (int q = 0; q < 8; q++) {
            float4 a0 = k0[q], a1 = k1[q];
            uh += qh[q*4+0]*a0.x + qh[q*4+1]*a0.y + qh[q*4+2]*a0.z + qh[q*4+3]*a0.w;
            vh += qh[q*4+0]*a1.x + qh[q*4+1]*a1.y + qh[q*4+2]*a1.z + qh[q*4+3]*a1.w;
        }
        #pragma unroll
        for (int m = 0; m < 12; m++) {
            const float4* ke = reinterpret_cast<const float4*>(s_ke + m * 32);
            float acc = 0.f;
            #pragma unroll
            for (int q = 0; q < 8; q++) {
                float4 k4 = ke[q];
                acc += qh[q*4+0]*k4.x + qh[q*4+1]*k4.y + qh[q*4+2]*k4.z + qh[q*4+3]*k4.w;
            }
            wh[m] = acc * scale;
        }
        uh *= scale; vh *= scale;
    }

    const float4* ve4 = reinterpret_cast<const float4*>(s_ve);

    // ---- main loop: process o in PAIRS so each s_ve read feeds two o's ----
    for (int op = 0; op < OO; op += 2) {
        const float4* tS  = reinterpret_cast<const float4*>(s_tokS + op * 12);
        const float4* tC  = reinterpret_cast<const float4*>(s_tokC + op * 12);
        const float4* tc2 = reinterpret_cast<const float4*>(s_c2   + op * 12);
        const float4* tgt = reinterpret_cast<const float4*>(s_gate + op * 12);

        float lg0[12], lg1[12];
        #pragma unroll
        for (int q = 0; q < 3; q++) {
            float4 S = tS[q], C = tC[q], c = tc2[q];
            lg0[q*4+0] = S.x*uh + C.x*vh + wh[q*4+0] + c.x;
            lg0[q*4+1] = S.y*uh + C.y*vh + wh[q*4+1] + c.y;
            lg0[q*4+2] = S.z*uh + C.z*vh + wh[q*4+2] + c.z;
            lg0[q*4+3] = S.w*uh + C.w*vh + wh[q*4+3] + c.w;
        }
        #pragma unroll
        for (int q = 0; q < 3; q++) {
            float4 S = tS[3+q], C = tC[3+q], c = tc2[3+q];
            lg1[q*4+0] = S.x*uh + C.x*vh + wh[q*4+0] + c.x;
            lg1[q*4+1] = S.y*uh + C.y*vh + wh[q*4+1] + c.y;
            lg1[q*4+2] = S.z*uh + C.z*vh + wh[q*4+2] + c.z;
            lg1[q*4+3] = S.w*uh + C.w*vh + wh[q*4+3] + c.w;
        }

        float mx0 = -1e30f, mx1 = -1e30f;
        #pragma unroll
        for (int m = 0; m < 12; m++) { mx0 = fmaxf(mx0, lg0[m]); mx1 = fmaxf(mx1, lg1[m]); }
        float sum0 = 0.f, sum1 = 0.f;
        #pragma unroll
        for (int m = 0; m < 12; m++) {
            lg0[m] = __expf(lg0[m] - mx0); sum0 += lg0[m];
            lg1[m] = __expf(lg1[m] - mx1); sum1 += lg1[m];
        }
        float inv0 = 1.f / sum0, inv1 = 1.f / sum1;
        #pragma unroll
        for (int m = 0; m < 12; m++) { lg0[m] *= inv0; lg1[m] *= inv1; }

        // attn writes [B,O,N,M] (write-once stream -> nontemporal)
        size_t abase0 = ((size_t)(b * OO + op) * NN + n) * MM;
        size_t abase1 = abase0 + (size_t)NN * MM;
        if (g == 0) {
            nt_store4(outAttn + abase0, lg0[0], lg0[1], lg0[2], lg0[3]);
            nt_store4(outAttn + abase1, lg1[0], lg1[1], lg1[2], lg1[3]);
        } else if (g == 1) {
            nt_store4(outAttn + abase0 + 4, lg0[4], lg0[5], lg0[6], lg0[7]);
            nt_store4(outAttn + abase1 + 4, lg1[4], lg1[5], lg1[6], lg1[7]);
        } else if (g == 2) {
            nt_store4(outAttn + abase0 + 8, lg0[8], lg0[9], lg0[10], lg0[11]);
            nt_store4(outAttn + abase1 + 8, lg1[8], lg1[9], lg1[10], lg1[11]);
        }

        // fold gate into attn weights (in place)
        #pragma unroll
        for (int q = 0; q < 3; q++) {
            float4 g0 = tgt[q], g1 = tgt[3+q];
            lg0[q*4+0] *= g0.x; lg0[q*4+1] *= g0.y; lg0[q*4+2] *= g0.z; lg0[q*4+3] *= g0.w;
            lg1[q*4+0] *= g1.x; lg1[q*4+1] *= g1.y; lg1[q*4+2] *= g1.z; lg1[q*4+3] *= g1.w;
        }

        // delta + H_time for BOTH o's off one s_ve read; chunk-interleaved
        // stores: instruction jj writes float4 at d-offset (g + 4*jj)*4 ->
        // the wave covers 16 fully-written 64B segments per instruction.
        size_t hbase = ((size_t)(b * OO + op) * NN + n) * DD;
        float* outp0 = outH + hbase;
        float* outp1 = outH + hbase + (size_t)NN * DD;
        #pragma unroll
        for (int jj = 0; jj < 4; jj++) {
            float ax0=0.f, ay0=0.f, az0=0.f, aw0=0.f;
            float ax1=0.f, ay1=0.f, az1=0.f, aw1=0.f;
            #pragma unroll
            for (int m = 0; m < 12; m++) {
                float4 vv = ve4[m * 16 + g + 4 * jj];
                ax0 += lg0[m]*vv.x; ay0 += lg0[m]*vv.y;
                az0 += lg0[m]*vv.z; aw0 += lg0[m]*vv.w;
                ax1 += lg1[m]*vv.x; ay1 += lg1[m]*vv.y;
                az1 += lg1[m]*vv.z; aw1 += lg1[m]*vv.w;
            }
            int off = (g + 4 * jj) * 4;
            nt_store4(outp0 + off,
                      h[jj*4+0] + 0.1f*ax0, h[jj*4+1] + 0.1f*ay0,
                      h[jj*4+2] + 0.1f*az0, h[jj*4+3] + 0.1f*aw0);
            nt_store4(outp1 + off,
                      h[jj*4+0] + 0.1f*ax1, h[jj*4+1] + 0.1f*ay1,
                      h[jj*4+2] + 0.1f*az1, h[jj*4+3] + 0.1f*aw1);
        }
    }
}

extern "C" void kernel_launch(void* const* d_in, const int* in_sizes, int n_in,
                              void* d_out, int out_size, void* d_ws, size_t ws_size,
                              hipStream_t stream) {
    const float* H        = (const float*)d_in[0];
    const float* ts_out   = (const float*)d_in[1];
    const float* step_emb = (const float*)d_in[2];
    const float* key_emb  = (const float*)d_in[3];
    const float* val_emb  = (const float*)d_in[4];
    const float* Wk       = (const float*)d_in[5];
    const float* Wg       = (const float*)d_in[6];
    const float* bg       = (const float*)d_in[7];
    const float* Wq       = (const float*)d_in[8];
    const float* bq       = (const float*)d_in[9];
    float* outp = (float*)d_out;

    dim3 grid(NN / 64, BB);
    stta_kernel<<<grid, 256, 0, stream>>>(H, ts_out, step_emb, key_emb, val_emb,
                                          Wk, Wg, bg, Wq, bq, outp);
}

// Round 3
// 272.263 us; speedup vs baseline: 1.2022x; 1.2022x over previous
//
#include <hip/hip_runtime.h>
#include <math.h>

#define BB 16
#define NN 4096
#define DD 64
#define OO 12
#define SS 32
#define MM 12
#define AA 32

// out layout: H_time [B,O,N,D] | attn [B,O,N,M] | gate [B,O,M]
__global__ __launch_bounds__(256, 4) void stta_kernel(
    const float* __restrict__ H, const float* __restrict__ ts_out,
    const float* __restrict__ step_emb, const float* __restrict__ key_emb,
    const float* __restrict__ val_emb, const float* __restrict__ Wk,
    const float* __restrict__ Wg, const float* __restrict__ bgp,
    const float* __restrict__ Wq, const float* __restrict__ bq,
    float* __restrict__ out)
{
    const int b = blockIdx.y;
    const int n0 = blockIdx.x * 64;
    const int tid = threadIdx.x;

    __shared__ __align__(16) float s_wq[32 * 64];       // Wq[a][d], d<64
    __shared__ __align__(16) float s_ke[MM * AA];       // key_emb[m][a]
    __shared__ __align__(16) float s_ve[MM * DD];       // val_emb[m][d]
    __shared__ __align__(16) float s_wk0[32];
    __shared__ __align__(16) float s_wk1[32];
    __shared__ __align__(16) float s_tokS[OO * MM];
    __shared__ __align__(16) float s_tokC[OO * MM];
    __shared__ __align__(16) float s_gate[OO * MM];
    __shared__ __align__(16) float s_qs[OO * AA];       // qs[o][a]
    __shared__ __align__(16) float s_c2[OO * MM];       // scale * (qs[o] . key[o,m])

    float* outH    = out;
    float* outAttn = out + (size_t)BB * OO * NN * DD;
    float* outGate = outAttn + (size_t)BB * OO * NN * MM;

    const float scale = 0.17677669529663687f; // 1/sqrt(32)

    // ---- staging (vectorized float4 copies) ----
    {
        float4* dst = reinterpret_cast<float4*>(s_wq);
        for (int i = tid; i < 512; i += 256) {
            int a = i >> 4, dq = i & 15;
            dst[i] = reinterpret_cast<const float4*>(Wq + a * 96)[dq];
        }
    }
    {
        float4* dst = reinterpret_cast<float4*>(s_ke);
        const float4* src = reinterpret_cast<const float4*>(key_emb);
        for (int i = tid; i < (MM * AA) / 4; i += 256) dst[i] = src[i];
    }
    {
        float4* dst = reinterpret_cast<float4*>(s_ve);
        const float4* src = reinterpret_cast<const float4*>(val_emb);
        for (int i = tid; i < (MM * DD) / 4; i += 256) dst[i] = src[i];
    }
    if (tid < 32) { s_wk0[tid] = Wk[tid * 2]; s_wk1[tid] = Wk[tid * 2 + 1]; }

    const float wg0 = Wg[0], wg1 = Wg[1], bg0 = bgp[0];
    for (int i = tid; i < OO * MM; i += 256) {
        int o = i / MM, m = i - o * MM;
        float phase = ts_out[(b * OO + o) * 2 + (m < 8 ? 0 : 1)];
        float k = (m < 8) ? (float)(m + 1) : (float)(m - 7);
        float ang = 6.283185307179586f * phase * k;
        float sv = sinf(ang), cv = cosf(ang);
        s_tokS[i] = sv; s_tokC[i] = cv;
        float gv = tanhf(sv * wg0 + cv * wg1 + bg0);
        s_gate[i] = gv;
        if (blockIdx.x == 0) outGate[(b * OO + o) * MM + m] = gv;
    }
    for (int e = tid; e < OO * AA; e += 256) {
        int o = e >> 5, a = e & 31;
        float acc = bq[a];
        const float* se = step_emb + (b * OO + o) * SS;
        const float* wq = Wq + a * 96 + 64;
        #pragma unroll
        for (int s = 0; s < SS; s++) acc += se[s] * wq[s];
        s_qs[e] = acc;
    }
    __syncthreads();

    // ---- c2[o][m] = scale * (qs[o] . key[o,m]) ----
    for (int i = tid; i < OO * MM; i += 256) {
        int o = i / MM, m = i - o * MM;
        float S = s_tokS[i], C = s_tokC[i];
        float acc = 0.f;
        const float* qs = s_qs + o * 32;
        const float* ke = s_ke + m * 32;
        #pragma unroll
        for (int a = 0; a < 32; a++)
            acc += qs[a] * (S * s_wk0[a] + C * s_wk1[a] + ke[a]);
        s_c2[i] = acc * scale;
    }
    __syncthreads();

    const int nl = tid >> 2, g = tid & 3;
    const int n = n0 + nl;

    // ---- load my 16 H values, chunk-interleaved: thread owns d-chunks
    //      {g, g+4, g+8, g+12}. For a fixed jj the wave's 64 lanes cover
    //      full 64B segments (4 lanes x 16B contiguous). ----
    const float4* hrow = reinterpret_cast<const float4*>(H + ((size_t)b * NN + n) * DD);
    float h[16];
    #pragma unroll
    for (int jj = 0; jj < 4; jj++) {
        float4 v = hrow[g + 4 * jj];
        h[jj*4+0] = v.x; h[jj*4+1] = v.y; h[jj*4+2] = v.z; h[jj*4+3] = v.w;
    }

    // ---- qh partials over my 16 d's, butterfly over the 4-lane group,
    //      then project to (uh, vh, wh[12]) — logits are linear in qh ----
    float uh = 0.f, vh = 0.f;
    float wh[12] = {0,0,0,0,0,0,0,0,0,0,0,0};
    {
        float qh[32];
        #pragma unroll
        for (int a = 0; a < 32; a++) {
            const float4* wq4 = reinterpret_cast<const float4*>(s_wq + a * 64);
            float acc = 0.f;
            #pragma unroll
            for (int jj = 0; jj < 4; jj++) {
                float4 w = wq4[g + 4 * jj];
                acc += h[jj*4+0]*w.x + h[jj*4+1]*w.y + h[jj*4+2]*w.z + h[jj*4+3]*w.w;
            }
            qh[a] = acc;
        }
        #pragma unroll
        for (int a = 0; a < 32; a++) qh[a] += __shfl_xor(qh[a], 1);
        #pragma unroll
        for (int a = 0; a < 32; a++) qh[a] += __shfl_xor(qh[a], 2);

        const float4* k0 = reinterpret_cast<const float4*>(s_wk0);
        const float4* k1 = reinterpret_cast<const float4*>(s_wk1);
        #pragma unroll
        for (int q = 0; q < 8; q++) {
            float4 a0 = k0[q], a1 = k1[q];
            uh += qh[q*4+0]*a0.x + qh[q*4+1]*a0.y + qh[q*4+2]*a0.z + qh[q*4+3]*a0.w;
            vh += qh[q*4+0]*a1.x + qh[q*4+1]*a1.y + qh[q*4+2]*a1.z + qh[q*4+3]*a1.w;
        }
        #pragma unroll
        for (int m = 0; m < 12; m++) {
            const float4* ke = reinterpret_cast<const float4*>(s_ke + m * 32);
            float acc = 0.f;
            #pragma unroll
            for (int q = 0; q < 8; q++) {
                float4 k4 = ke[q];
                acc += qh[q*4+0]*k4.x + qh[q*4+1]*k4.y + qh[q*4+2]*k4.z + qh[q*4+3]*k4.w;
            }
            wh[m] = acc * scale;
        }
        uh *= scale; vh *= scale;
    }

    const float4* ve4 = reinterpret_cast<const float4*>(s_ve);

    // ---- main loop: process o in PAIRS so each s_ve read feeds two o's ----
    for (int op = 0; op < OO; op += 2) {
        const float4* tS  = reinterpret_cast<const float4*>(s_tokS + op * 12);
        const float4* tC  = reinterpret_cast<const float4*>(s_tokC + op * 12);
        const float4* tc2 = reinterpret_cast<const float4*>(s_c2   + op * 12);
        const float4* tgt = reinterpret_cast<const float4*>(s_gate + op * 12);

        float lg0[12], lg1[12];
        #pragma unroll
        for (int q = 0; q < 3; q++) {
            float4 S = tS[q], C = tC[q], c = tc2[q];
            lg0[q*4+0] = S.x*uh + C.x*vh + wh[q*4+0] + c.x;
            lg0[q*4+1] = S.y*uh + C.y*vh + wh[q*4+1] + c.y;
            lg0[q*4+2] = S.z*uh + C.z*vh + wh[q*4+2] + c.z;
            lg0[q*4+3] = S.w*uh + C.w*vh + wh[q*4+3] + c.w;
        }
        #pragma unroll
        for (int q = 0; q < 3; q++) {
            float4 S = tS[3+q], C = tC[3+q], c = tc2[3+q];
            lg1[q*4+0] = S.x*uh + C.x*vh + wh[q*4+0] + c.x;
            lg1[q*4+1] = S.y*uh + C.y*vh + wh[q*4+1] + c.y;
            lg1[q*4+2] = S.z*uh + C.z*vh + wh[q*4+2] + c.z;
            lg1[q*4+3] = S.w*uh + C.w*vh + wh[q*4+3] + c.w;
        }

        float mx0 = -1e30f, mx1 = -1e30f;
        #pragma unroll
        for (int m = 0; m < 12; m++) { mx0 = fmaxf(mx0, lg0[m]); mx1 = fmaxf(mx1, lg1[m]); }
        float sum0 = 0.f, sum1 = 0.f;
        #pragma unroll
        for (int m = 0; m < 12; m++) {
            lg0[m] = __expf(lg0[m] - mx0); sum0 += lg0[m];
            lg1[m] = __expf(lg1[m] - mx1); sum1 += lg1[m];
        }
        float inv0 = 1.f / sum0, inv1 = 1.f / sum1;
        #pragma unroll
        for (int m = 0; m < 12; m++) { lg0[m] *= inv0; lg1[m] *= inv1; }

        // attn writes [B,O,N,M] (plain cached stores — L2/L3 absorbs)
        size_t abase0 = ((size_t)(b * OO + op) * NN + n) * MM;
        size_t abase1 = abase0 + (size_t)NN * MM;
        if (g == 0) {
            *reinterpret_cast<float4*>(outAttn + abase0) =
                make_float4(lg0[0], lg0[1], lg0[2], lg0[3]);
            *reinterpret_cast<float4*>(outAttn + abase1) =
                make_float4(lg1[0], lg1[1], lg1[2], lg1[3]);
        } else if (g == 1) {
            *reinterpret_cast<float4*>(outAttn + abase0 + 4) =
                make_float4(lg0[4], lg0[5], lg0[6], lg0[7]);
            *reinterpret_cast<float4*>(outAttn + abase1 + 4) =
                make_float4(lg1[4], lg1[5], lg1[6], lg1[7]);
        } else if (g == 2) {
            *reinterpret_cast<float4*>(outAttn + abase0 + 8) =
                make_float4(lg0[8], lg0[9], lg0[10], lg0[11]);
            *reinterpret_cast<float4*>(outAttn + abase1 + 8) =
                make_float4(lg1[8], lg1[9], lg1[10], lg1[11]);
        }

        // fold gate into attn weights (in place)
        #pragma unroll
        for (int q = 0; q < 3; q++) {
            float4 g0 = tgt[q], g1 = tgt[3+q];
            lg0[q*4+0] *= g0.x; lg0[q*4+1] *= g0.y; lg0[q*4+2] *= g0.z; lg0[q*4+3] *= g0.w;
            lg1[q*4+0] *= g1.x; lg1[q*4+1] *= g1.y; lg1[q*4+2] *= g1.z; lg1[q*4+3] *= g1.w;
        }

        // delta + H_time for BOTH o's off one s_ve read; chunk-interleaved
        // stores: instruction jj writes float4 at d-offset (g + 4*jj)*4 ->
        // the wave covers 16 fully-written 64B segments per instruction.
        size_t hbase = ((size_t)(b * OO + op) * NN + n) * DD;
        float4* outp0 = reinterpret_cast<float4*>(outH + hbase);
        float4* outp1 = reinterpret_cast<float4*>(outH + hbase + (size_t)NN * DD);
        #pragma unroll
        for (int jj = 0; jj < 4; jj++) {
            float ax0=0.f, ay0=0.f, az0=0.f, aw0=0.f;
            float ax1=0.f, ay1=0.f, az1=0.f, aw1=0.f;
            #pragma unroll
            for (int m = 0; m < 12; m++) {
                float4 vv = ve4[m * 16 + g + 4 * jj];
                ax0 += lg0[m]*vv.x; ay0 += lg0[m]*vv.y;
                az0 += lg0[m]*vv.z; aw0 += lg0[m]*vv.w;
                ax1 += lg1[m]*vv.x; ay1 += lg1[m]*vv.y;
                az1 += lg1[m]*vv.z; aw1 += lg1[m]*vv.w;
            }
            outp0[g + 4*jj] = make_float4(h[jj*4+0] + 0.1f*ax0, h[jj*4+1] + 0.1f*ay0,
                                          h[jj*4+2] + 0.1f*az0, h[jj*4+3] + 0.1f*aw0);
            outp1[g + 4*jj] = make_float4(h[jj*4+0] + 0.1f*ax1, h[jj*4+1] + 0.1f*ay1,
                                          h[jj*4+2] + 0.1f*az1, h[jj*4+3] + 0.1f*aw1);
        }
    }
}

extern "C" void kernel_launch(void* const* d_in, const int* in_sizes, int n_in,
                              void* d_out, int out_size, void* d_ws, size_t ws_size,
                              hipStream_t stream) {
    const float* H        = (const float*)d_in[0];
    const float* ts_out   = (const float*)d_in[1];
    const float* step_emb = (const float*)d_in[2];
    const float* key_emb  = (const float*)d_in[3];
    const float* val_emb  = (const float*)d_in[4];
    const float* Wk       = (const float*)d_in[5];
    const float* Wg       = (const float*)d_in[6];
    const float* bg       = (const float*)d_in[7];
    const float* Wq       = (const float*)d_in[8];
    const float* bq       = (const float*)d_in[9];
    float* outp = (float*)d_out;

    dim3 grid(NN / 64, BB);
    stta_kernel<<<grid, 256, 0, stream>>>(H, ts_out, step_emb, key_emb, val_emb,
                                          Wk, Wg, bg, Wq, bq, outp);
}